// Round 19
// baseline (358.508 us; speedup 1.0000x reference)
//
#include <hip/hip_runtime.h>

#define T_DIM 2048
#define B_DIM 16
#define E_DIM 1024
#define CD    1024
#define NH    16
#define KSZ   31
#define M_DIM 32768
#define SLICE 131072            // 2048*64 elements per (b,h) slice
#define BSTRIDE 2097152         // 2048*1024 = 16*SLICE

typedef unsigned int u32;
typedef unsigned short u16;
typedef __attribute__((ext_vector_type(8))) __bf16 bf16x8;
typedef __attribute__((ext_vector_type(4))) float f32x4;
typedef __attribute__((ext_vector_type(4))) float fvec4;
typedef __attribute__((ext_vector_type(8))) unsigned short us8;
typedef __attribute__((ext_vector_type(4))) unsigned short us4;
typedef __attribute__((ext_vector_type(4))) unsigned int ui4;

__device__ __forceinline__ float bf2f(u16 u) {
  union { float f; u32 i; } c; c.i = ((u32)u) << 16; return c.f;
}
__device__ __forceinline__ u16 f2bf(float f) {
  union { float f; u32 i; } c; c.f = f;
  u32 u = c.i;
  u += 0x7fffu + ((u >> 16) & 1u);   // RNE
  return (u16)(u >> 16);
}

#define GLDS(gp, lp)                                                        \
  __builtin_amdgcn_global_load_lds(                                         \
      (__attribute__((address_space(1))) void*)(gp),                        \
      (__attribute__((address_space(3))) void*)(lp), 16, 0, 0)

// ---------------------------------------------------------------- prep: one launch for all pre-passes
__global__ __launch_bounds__(256) void prep(const float* __restrict__ x,
                                            const float* __restrict__ w1,
                                            const float* __restrict__ w2,
                                            const float* __restrict__ ww,
                                            u16* __restrict__ xbt,
                                            u16* __restrict__ w1b,
                                            u16* __restrict__ w2b,
                                            u16* __restrict__ wwb,
                                            u16* __restrict__ zreg)
{
  const int NX = (T_DIM * B_DIM * E_DIM) / 4;          // 8388608
  const int N1 = NX + (CD * E_DIM) / 4;                // +262144
  const int N2 = N1 + (E_DIM * CD) / 4;                // +262144
  const int N3 = N2 + (NH * KSZ * CD) / 4;             // +126976
  int i = blockIdx.x * 256 + threadIdx.x;
  if (i < NX) {
    int rr = i >> 8, c = i & 255;                      // row t*16+b, chunk within row
    int t = rr >> 4, b = rr & 15;
    fvec4 v = ((const fvec4*)x)[i];
    us4 o;
    o[0] = f2bf(v[0]); o[1] = f2bf(v[1]); o[2] = f2bf(v[2]); o[3] = f2bf(v[3]);
    ((us4*)xbt)[(size_t)(b * T_DIM + t) * 256 + c] = o;
  } else if (i < N1) {
    int j = i - NX;
    fvec4 v = ((const fvec4*)w1)[j];
    us4 o;
    o[0] = f2bf(v[0]); o[1] = f2bf(v[1]); o[2] = f2bf(v[2]); o[3] = f2bf(v[3]);
    ((us4*)w1b)[j] = o;
  } else if (i < N2) {
    int j = i - N1;
    fvec4 v = ((const fvec4*)w2)[j];
    us4 o;
    o[0] = f2bf(v[0]); o[1] = f2bf(v[1]); o[2] = f2bf(v[2]); o[3] = f2bf(v[3]);
    ((us4*)w2b)[j] = o;
  } else if (i < N3) {
    int j = i - N2;
    fvec4 v = ((const fvec4*)ww)[j];
    us4 o;
    o[0] = f2bf(v[0]); o[1] = f2bf(v[1]); o[2] = f2bf(v[2]); o[3] = f2bf(v[3]);
    ((us4*)wwb)[j] = o;
  } else {
    ((ui4*)zreg)[i - N3] = (ui4)(0u);
  }
}

// ---------------------------------------------------------------- 128x256 bf16 MFMA GEMM, 48 KB LDS -> 2 blocks/CU
// (unchanged from R14 — the TLP variant that dropped GEMMs to ~72-87 us)
template<int OUT_MODE, int GUARD_N, int A_CONV>
__global__ __launch_bounds__(256, 2) void gemm_tlp(
    const u16* __restrict__ A, const u16* __restrict__ B,
    const float* __restrict__ bias, void* __restrict__ Cout,
    int N, int K, int ldc, int ntn)
{
  __shared__ u16 sA[2][128 * 32];    // 8 KB per slot
  __shared__ u16 sB[2][256 * 32];    // 16 KB per slot; total 48 KB
  const int tid = threadIdx.x;
  const int lane = tid & 63;
  const int wid = tid >> 6;          // 0..3
  const int wc = wid;                // N quarter; M is whole tile

  const int swz = (blockIdx.x & 7) * (gridDim.x >> 3) + (blockIdx.x >> 3);
  const int bm = (swz / ntn) * 128;
  const int bn = (swz % ntn) * 256;

  const int srow = tid >> 2;              // 0..63
  const int scol = (tid & 3) * 8;         // 0,8,16,24 (u16)
  const int scols = scol ^ (((srow >> 1) & 3) << 3);   // pre-swizzled source col
  const int sdst = srow * 32 + scol;                    // + it*2048

  const u16* gA2[2];
  #pragma unroll
  for (int it = 0; it < 2; it++) {
    int rr = bm + it * 64 + srow;
    if (A_CONV)
      gA2[it] = A + (size_t)(rr >> 11) * BSTRIDE + (size_t)(rr & 2047) * 64 + scols;
    else
      gA2[it] = A + (size_t)rr * K + scols;
  }
  const u16* gB2[4];
  #pragma unroll
  for (int it = 0; it < 4; it++) {
    int br = bn + it * 64 + srow;
    if (GUARD_N) br = min(br, N - 1);
    gB2[it] = B + (size_t)br * K + scols;
  }

  auto stage = [&](int ph) {
    int slot = ph & 1;
    int kt = ph >> 1, kh = ph & 1;
    size_t koA = A_CONV ? (size_t)kt * SLICE + kh * 32 : (size_t)kt * 64 + kh * 32;
    size_t koB = (size_t)kt * 64 + kh * 32;
    GLDS(gA2[0] + koA, &sA[slot][0 * 2048 + sdst]);
    GLDS(gA2[1] + koA, &sA[slot][1 * 2048 + sdst]);
    GLDS(gB2[0] + koB, &sB[slot][0 * 2048 + sdst]);
    GLDS(gB2[1] + koB, &sB[slot][1 * 2048 + sdst]);
    GLDS(gB2[2] + koB, &sB[slot][2 * 2048 + sdst]);
    GLDS(gB2[3] + koB, &sB[slot][3 * 2048 + sdst]);
  };

  f32x4 acc[8][4];
  #pragma unroll
  for (int i = 0; i < 8; i++)
    #pragma unroll
    for (int j = 0; j < 4; j++) acc[i][j] = (f32x4)(0.0f);

  const int fr = lane & 15;
  const int g8 = (lane >> 4) * 8;          // k-chunk (u16) within 32-k half

  auto ard = [&](const u16* base, int row) -> bf16x8 {
    return *(const bf16x8*)&base[row * 32 + (g8 ^ ((((row >> 1) & 3)) << 3))];
  };

  const int NP = K >> 5;                   // phases = K-halves

  stage(0);
  asm volatile("s_waitcnt vmcnt(0)" ::: "memory");
  __builtin_amdgcn_s_barrier();

  for (int ph = 0; ph < NP; ph++) {
    const int cur = ph & 1;
    bf16x8 bF[4], aG[8];
    #pragma unroll
    for (int n = 0; n < 4; n++) bF[n] = ard(&sB[cur][0], wc * 64 + n * 16 + fr);
    #pragma unroll
    for (int mi = 0; mi < 8; mi++) aG[mi] = ard(&sA[cur][0], mi * 16 + fr);
    if (ph + 1 < NP) stage(ph + 1);
    asm volatile("s_waitcnt lgkmcnt(0)" ::: "memory");
    __builtin_amdgcn_sched_barrier(0);
    __builtin_amdgcn_s_setprio(1);
    #pragma unroll
    for (int mi = 0; mi < 8; mi++)
      #pragma unroll
      for (int n = 0; n < 4; n++)
        acc[mi][n] = __builtin_amdgcn_mfma_f32_16x16x32_bf16(aG[mi], bF[n], acc[mi][n], 0, 0, 0);
    __builtin_amdgcn_s_setprio(0);
    __builtin_amdgcn_sched_barrier(0);
    asm volatile("s_waitcnt vmcnt(0)" ::: "memory");
    __builtin_amdgcn_s_barrier();
  }

  const int orow0 = bm + (lane >> 4) * 4;      // C/D: col=lane&15, row=(lane>>4)*4+q
  const int ocol0 = bn + wc * 64 + fr;
  #pragma unroll
  for (int m = 0; m < 8; m++) {
    #pragma unroll
    for (int n = 0; n < 4; n++) {
      #pragma unroll
      for (int q = 0; q < 4; q++) {
        int row = orow0 + m * 16 + q;
        int col = ocol0 + n * 16;
        if (!GUARD_N || col < N) {
          float v = acc[m][n][q] + bias[col];
          if (OUT_MODE == 1) {
            ((u16*)Cout)[(size_t)row * ldc + col] = f2bf(v);
          } else if (OUT_MODE == 2) {               // wt bf16 [b][h][t][32]
            int bb = row >> 11, t = row & 2047;
            int hh = col / 31, kk = col - hh * 31;  // compile-time magic div
            ((u16*)Cout)[((size_t)((bb * NH + hh) * T_DIM + t)) * 32 + kk] = f2bf(v);
          } else {                                  // 3: conv layout bf16
            int bb = row >> 11, t = row & 2047;
            ((u16*)Cout)[(size_t)((bb << 4) + (col >> 6)) * SLICE + (size_t)t * 64 + (col & 63)] = f2bf(v);
          }
        }
      }
    }
  }
}

// ---------------------------------------------------------------- dynamic conv + fused softmax (TT=128, pair-share v3)
// = R18 pair-share, with wl stored as bf16 (stride-33 u16) -> LDS 53.8->44 KB
// -> 3 blocks/CU (occupancy 21->~31%). w-tap group byte-starts 0,132,264,...
// hit distinct banks -> broadcasts stay conflict-free. ob conflicts (4.2M) are
// inherent to full-row group writes (each 128B row covers all 32 banks) and
// cost ~256 cyc/wave — accepted.
__global__ __launch_bounds__(256) void dconv(const u16* __restrict__ h1,
                                             const u16* __restrict__ wt,
                                             const u16* __restrict__ zreg,
                                             u16* __restrict__ outc)
{
  constexpr int TT = 128, HALO = 30, SW = 33;
  int bid = blockIdx.x;
  int tt = bid & 15;            // T/128 = 16
  int b  = (bid >> 4) & 15;
  int h  = bid >> 8;            // 0..15
  int s  = b * 16 + h;
  int t0 = tt * TT;
  __shared__ u16 hl[(TT + HALO) * 64];   // 19.75 KB
  __shared__ u16 wl[TT * SW];            // 8.25 KB bf16 weights
  __shared__ u16 ob[TT * 64];            // 16 KB swizzled out-buffer; total 44 KB
  int tid = threadIdx.x;

  const u16* slice = h1 + (size_t)s * SLICE;
  #pragma unroll
  for (int it = 0; it < 5; it++) {
    int c = it * 256 + tid;
    if (c < (TT + HALO) * 8) {
      int row = t0 - HALO + (c >> 3);
      const u16* src = slice + (size_t)row * 64 + (c & 7) * 8;
      if (row < 0) src = zreg + (c & 7) * 8;      // zeroed scratch
      GLDS(src, hl + c * 8);
    }
  }
  {
    const u16* wsrc = wt + ((size_t)s * T_DIM + t0) * 32;   // contiguous 8 KB bf16
    #pragma unroll
    for (int it = 0; it < 2; it++) {
      int j = (it * 256 + tid) * 8;
      us8 v = *(const us8*)(wsrc + j);
      int row = j >> 5, col = j & 31;
      #pragma unroll
      for (int e = 0; e < 8; e++) wl[row * SW + col + e] = v[e];
    }
  }
  __syncthreads();

  // fused softmax over the 128 staged rows (bf16 in LDS; f32 math in regs)
  if (tid < TT) {
    u16* p = wl + tid * SW;
    float v[KSZ];
    float mx = -1e30f;
    #pragma unroll
    for (int k = 0; k < KSZ; k++) { v[k] = bf2f(p[k]); mx = fmaxf(mx, v[k]); }
    float sum = 0.f;
    #pragma unroll
    for (int k = 0; k < KSZ; k++) { v[k] = __expf(v[k] - mx); sum += v[k]; }
    float inv = 1.0f / sum;
    #pragma unroll
    for (int k = 0; k < KSZ; k++) p[k] = f2bf(v[k] * inv);
  }
  __syncthreads();

  const int rb = (tid & 7) * 8;      // channel sub-block
  const int tl = tid >> 3;           // 0..31

  #pragma unroll
  for (int half = 0; half < 2; half++) {
    const int pb = half * 64 + tl * 2;     // pair base row
    float acc0[8], acc1[8];
    #pragma unroll
    for (int e = 0; e < 8; e++) { acc0[e] = 0.f; acc1[e] = 0.f; }
    const u16* w0 = wl + pb * SW;
    const u16* w1 = w0 + SW;
    const u16* hb = hl + pb * 64 + rb;
    #pragma unroll
    for (int j = 0; j < 32; j++) {         // shared input rows pb..pb+31
      us8 hv = *(const us8*)(hb + j * 64);
      float hf[8];
      #pragma unroll
      for (int e = 0; e < 8; e++) hf[e] = bf2f(hv[e]);
      if (j <= 30) {
        float w = bf2f(w0[j]);
        #pragma unroll
        for (int e = 0; e < 8; e++) acc0[e] += w * hf[e];
      }
      if (j >= 1) {
        float w = bf2f(w1[j - 1]);
        #pragma unroll
        for (int e = 0; e < 8; e++) acc1[e] += w * hf[e];
      }
    }
    // store pair immediately into swizzled ob (no res[] -> low VGPR)
    us8 o0, o1;
    #pragma unroll
    for (int e = 0; e < 8; e++) { o0[e] = f2bf(acc0[e]); o1[e] = f2bf(acc1[e]); }
    *(us8*)(&ob[pb * 64 + (rb ^ ((pb & 7) << 3))]) = o0;
    *(us8*)(&ob[(pb + 1) * 64 + (rb ^ (((pb + 1) & 7) << 3))]) = o1;
  }
  __syncthreads();

  // contiguous global stores: byte offset = q*4096 + tid*16 (4 KB span/instr)
  #pragma unroll
  for (int q = 0; q < 4; q++) {
    const int tb = tl + q * 32;
    us8 o = *(const us8*)(&ob[tb * 64 + (rb ^ ((tb & 7) << 3))]);
    *(us8*)(outc + (size_t)s * SLICE + (size_t)(t0 + tb) * 64 + rb) = o;
  }
}

// ---------------------------------------------------------------- residual + LayerNorm (bf16 x + bf16 h)
__global__ __launch_bounds__(256) void ln_res(const u16* __restrict__ xb,
                                              const u16* __restrict__ hb,
                                              float* __restrict__ out,
                                              const float* __restrict__ gamma,
                                              const float* __restrict__ beta)
{
  int mp = blockIdx.x;                 // b*2048 + t
  int b = mp >> 11, t = mp & 2047;
  int xrow = t * 16 + b;
  const us4* xr = (const us4*)(xb + (size_t)mp * E_DIM);
  const us4* hr = (const us4*)(hb + (size_t)mp * E_DIM);
  fvec4* yr = (fvec4*)(out + (size_t)xrow * E_DIM);
  int tid = threadIdx.x;
  us4 hv = hr[tid];
  us4 xv = xr[tid];
  fvec4 s;
  #pragma unroll
  for (int e = 0; e < 4; e++) s[e] = bf2f(xv[e]) + bf2f(hv[e]);
  float sum = s[0] + s[1] + s[2] + s[3];
  float sq  = s[0]*s[0] + s[1]*s[1] + s[2]*s[2] + s[3]*s[3];
  #pragma unroll
  for (int off = 32; off >= 1; off >>= 1) {
    sum += __shfl_xor(sum, off, 64);
    sq  += __shfl_xor(sq, off, 64);
  }
  __shared__ float red[8];
  int lane = tid & 63, wid = tid >> 6;
  if (lane == 0) { red[wid] = sum; red[4 + wid] = sq; }
  __syncthreads();
  sum = red[0] + red[1] + red[2] + red[3];
  sq  = red[4] + red[5] + red[6] + red[7];
  float mean = sum * (1.0f / E_DIM);
  float var  = sq * (1.0f / E_DIM) - mean * mean;
  float rstd = rsqrtf(var + 1e-5f);
  fvec4 g = ((const fvec4*)gamma)[tid];
  fvec4 be = ((const fvec4*)beta)[tid];
  fvec4 o;
  #pragma unroll
  for (int e = 0; e < 4; e++) o[e] = (s[e] - mean) * rstd * g[e] + be[e];
  yr[tid] = o;
}

// ---------------------------------------------------------------- launcher
extern "C" void kernel_launch(void* const* d_in, const int* in_sizes, int n_in,
                              void* d_out, int out_size, void* d_ws, size_t ws_size,
                              hipStream_t stream)
{
  const float* x     = (const float*)d_in[0];
  const float* w1    = (const float*)d_in[1];
  const float* b1    = (const float*)d_in[2];
  const float* ww    = (const float*)d_in[3];
  const float* bw    = (const float*)d_in[4];
  const float* w2    = (const float*)d_in[5];
  const float* b2    = (const float*)d_in[6];
  const float* gamma = (const float*)d_in[7];
  const float* beta  = (const float*)d_in[8];
  float* out = (float*)d_out;

  char* ws = (char*)d_ws;
  u16*   xbt  = (u16*)(ws);                          // 64 MB  xb'[b][t][e] (kept for ln_res)
  u16*   h1p  = (u16*)(ws + ((size_t)64 << 20));     // 64 MB  h1'[s][t][64]; reused as h2'
  u16*   wt   = (u16*)(ws + ((size_t)128 << 20));    // 32 MB  wt[b][h][t][32] bf16 logits
  u16*   convp = (u16*)(ws + ((size_t)160 << 20));   // 64 MB  conv'
  u16*   w1b  = (u16*)(ws + ((size_t)224 << 20));    // 2 MB
  u16*   w2b  = (u16*)(ws + ((size_t)226 << 20));    // 2 MB
  u16*   wwb  = (u16*)(ws + ((size_t)228 << 20));    // ~1 MB
  u16*   zreg = (u16*)(ws + ((size_t)230 << 20));    // 4 KB zeroed
  u16*   h2p  = h1p;                                 // h1p dead after dconv

  prep<<<35313, 256, 0, stream>>>(x, w1, w2, ww, xbt, w1b, w2b, wwb, zreg);

  // h1' = x @ w1^T + b1   (conv-layout bf16); 256 M-tiles x 4 N-tiles
  gemm_tlp<3, 0, 0><<<1024, 256, 0, stream>>>(xbt, w1b, b1, h1p, CD, E_DIM, 0, 4);
  // wt[b][h][t][k] = h1' @ ww^T + bw   (bf16 logits, N=496 guarded); 256 x 2
  gemm_tlp<2, 1, 1><<<512, 256, 0, stream>>>(h1p, wwb, bw, wt, NH * KSZ, CD, 0, 2);
  dconv<<<4096, 256, 0, stream>>>(h1p, wt, zreg, convp);
  // h2' = conv' @ w2^T + b2   (bf16, rows m'); 256 x 4
  gemm_tlp<1, 0, 1><<<1024, 256, 0, stream>>>(convp, w2b, b2, h2p, E_DIM, CD, E_DIM, 4);
  ln_res<<<32768, 256, 0, stream>>>(xbt, h2p, out, gamma, beta);
}

// Round 20
// 346.640 us; speedup vs baseline: 1.0342x; 1.0342x over previous
//
#include <hip/hip_runtime.h>

#define T_DIM 2048
#define B_DIM 16
#define E_DIM 1024
#define CD    1024
#define NH    16
#define KSZ   31
#define M_DIM 32768
#define SLICE 131072            // 2048*64 elements per (b,h) slice
#define BSTRIDE 2097152         // 2048*1024 = 16*SLICE

typedef unsigned int u32;
typedef unsigned short u16;
typedef __attribute__((ext_vector_type(8))) __bf16 bf16x8;
typedef __attribute__((ext_vector_type(4))) float f32x4;
typedef __attribute__((ext_vector_type(4))) float fvec4;
typedef __attribute__((ext_vector_type(8))) unsigned short us8;
typedef __attribute__((ext_vector_type(4))) unsigned short us4;
typedef __attribute__((ext_vector_type(4))) unsigned int ui4;

__device__ __forceinline__ float bf2f(u16 u) {
  union { float f; u32 i; } c; c.i = ((u32)u) << 16; return c.f;
}
__device__ __forceinline__ u16 f2bf(float f) {
  union { float f; u32 i; } c; c.f = f;
  u32 u = c.i;
  u += 0x7fffu + ((u >> 16) & 1u);   // RNE
  return (u16)(u >> 16);
}

#define GLDS(gp, lp)                                                        \
  __builtin_amdgcn_global_load_lds(                                         \
      (__attribute__((address_space(1))) void*)(gp),                        \
      (__attribute__((address_space(3))) void*)(lp), 16, 0, 0)

// ---------------------------------------------------------------- prep: one launch for all pre-passes
__global__ __launch_bounds__(256) void prep(const float* __restrict__ x,
                                            const float* __restrict__ w1,
                                            const float* __restrict__ w2,
                                            const float* __restrict__ ww,
                                            u16* __restrict__ xbt,
                                            u16* __restrict__ w1b,
                                            u16* __restrict__ w2b,
                                            u16* __restrict__ wwb,
                                            u16* __restrict__ zreg)
{
  const int NX = (T_DIM * B_DIM * E_DIM) / 4;          // 8388608
  const int N1 = NX + (CD * E_DIM) / 4;                // +262144
  const int N2 = N1 + (E_DIM * CD) / 4;                // +262144
  const int N3 = N2 + (NH * KSZ * CD) / 4;             // +126976
  int i = blockIdx.x * 256 + threadIdx.x;
  if (i < NX) {
    int rr = i >> 8, c = i & 255;                      // row t*16+b, chunk within row
    int t = rr >> 4, b = rr & 15;
    fvec4 v = ((const fvec4*)x)[i];
    us4 o;
    o[0] = f2bf(v[0]); o[1] = f2bf(v[1]); o[2] = f2bf(v[2]); o[3] = f2bf(v[3]);
    ((us4*)xbt)[(size_t)(b * T_DIM + t) * 256 + c] = o;
  } else if (i < N1) {
    int j = i - NX;
    fvec4 v = ((const fvec4*)w1)[j];
    us4 o;
    o[0] = f2bf(v[0]); o[1] = f2bf(v[1]); o[2] = f2bf(v[2]); o[3] = f2bf(v[3]);
    ((us4*)w1b)[j] = o;
  } else if (i < N2) {
    int j = i - N1;
    fvec4 v = ((const fvec4*)w2)[j];
    us4 o;
    o[0] = f2bf(v[0]); o[1] = f2bf(v[1]); o[2] = f2bf(v[2]); o[3] = f2bf(v[3]);
    ((us4*)w2b)[j] = o;
  } else if (i < N3) {
    int j = i - N2;
    fvec4 v = ((const fvec4*)ww)[j];
    us4 o;
    o[0] = f2bf(v[0]); o[1] = f2bf(v[1]); o[2] = f2bf(v[2]); o[3] = f2bf(v[3]);
    ((us4*)wwb)[j] = o;
  } else {
    ((ui4*)zreg)[i - N3] = (ui4)(0u);
  }
}

// ---------------------------------------------------------------- 128x256 bf16 MFMA GEMM, 48 KB LDS -> 2 blocks/CU
// (unchanged from R14 — the TLP variant that dropped GEMMs to ~72-87 us)
template<int OUT_MODE, int GUARD_N, int A_CONV>
__global__ __launch_bounds__(256, 2) void gemm_tlp(
    const u16* __restrict__ A, const u16* __restrict__ B,
    const float* __restrict__ bias, void* __restrict__ Cout,
    int N, int K, int ldc, int ntn)
{
  __shared__ u16 sA[2][128 * 32];    // 8 KB per slot
  __shared__ u16 sB[2][256 * 32];    // 16 KB per slot; total 48 KB
  const int tid = threadIdx.x;
  const int lane = tid & 63;
  const int wid = tid >> 6;          // 0..3
  const int wc = wid;                // N quarter; M is whole tile

  const int swz = (blockIdx.x & 7) * (gridDim.x >> 3) + (blockIdx.x >> 3);
  const int bm = (swz / ntn) * 128;
  const int bn = (swz % ntn) * 256;

  const int srow = tid >> 2;              // 0..63
  const int scol = (tid & 3) * 8;         // 0,8,16,24 (u16)
  const int scols = scol ^ (((srow >> 1) & 3) << 3);   // pre-swizzled source col
  const int sdst = srow * 32 + scol;                    // + it*2048

  const u16* gA2[2];
  #pragma unroll
  for (int it = 0; it < 2; it++) {
    int rr = bm + it * 64 + srow;
    if (A_CONV)
      gA2[it] = A + (size_t)(rr >> 11) * BSTRIDE + (size_t)(rr & 2047) * 64 + scols;
    else
      gA2[it] = A + (size_t)rr * K + scols;
  }
  const u16* gB2[4];
  #pragma unroll
  for (int it = 0; it < 4; it++) {
    int br = bn + it * 64 + srow;
    if (GUARD_N) br = min(br, N - 1);
    gB2[it] = B + (size_t)br * K + scols;
  }

  auto stage = [&](int ph) {
    int slot = ph & 1;
    int kt = ph >> 1, kh = ph & 1;
    size_t koA = A_CONV ? (size_t)kt * SLICE + kh * 32 : (size_t)kt * 64 + kh * 32;
    size_t koB = (size_t)kt * 64 + kh * 32;
    GLDS(gA2[0] + koA, &sA[slot][0 * 2048 + sdst]);
    GLDS(gA2[1] + koA, &sA[slot][1 * 2048 + sdst]);
    GLDS(gB2[0] + koB, &sB[slot][0 * 2048 + sdst]);
    GLDS(gB2[1] + koB, &sB[slot][1 * 2048 + sdst]);
    GLDS(gB2[2] + koB, &sB[slot][2 * 2048 + sdst]);
    GLDS(gB2[3] + koB, &sB[slot][3 * 2048 + sdst]);
  };

  f32x4 acc[8][4];
  #pragma unroll
  for (int i = 0; i < 8; i++)
    #pragma unroll
    for (int j = 0; j < 4; j++) acc[i][j] = (f32x4)(0.0f);

  const int fr = lane & 15;
  const int g8 = (lane >> 4) * 8;          // k-chunk (u16) within 32-k half

  auto ard = [&](const u16* base, int row) -> bf16x8 {
    return *(const bf16x8*)&base[row * 32 + (g8 ^ ((((row >> 1) & 3)) << 3))];
  };

  const int NP = K >> 5;                   // phases = K-halves

  stage(0);
  asm volatile("s_waitcnt vmcnt(0)" ::: "memory");
  __builtin_amdgcn_s_barrier();

  for (int ph = 0; ph < NP; ph++) {
    const int cur = ph & 1;
    bf16x8 bF[4], aG[8];
    #pragma unroll
    for (int n = 0; n < 4; n++) bF[n] = ard(&sB[cur][0], wc * 64 + n * 16 + fr);
    #pragma unroll
    for (int mi = 0; mi < 8; mi++) aG[mi] = ard(&sA[cur][0], mi * 16 + fr);
    if (ph + 1 < NP) stage(ph + 1);
    asm volatile("s_waitcnt lgkmcnt(0)" ::: "memory");
    __builtin_amdgcn_sched_barrier(0);
    __builtin_amdgcn_s_setprio(1);
    #pragma unroll
    for (int mi = 0; mi < 8; mi++)
      #pragma unroll
      for (int n = 0; n < 4; n++)
        acc[mi][n] = __builtin_amdgcn_mfma_f32_16x16x32_bf16(aG[mi], bF[n], acc[mi][n], 0, 0, 0);
    __builtin_amdgcn_s_setprio(0);
    __builtin_amdgcn_sched_barrier(0);
    asm volatile("s_waitcnt vmcnt(0)" ::: "memory");
    __builtin_amdgcn_s_barrier();
  }

  const int orow0 = bm + (lane >> 4) * 4;      // C/D: col=lane&15, row=(lane>>4)*4+q
  const int ocol0 = bn + wc * 64 + fr;
  #pragma unroll
  for (int m = 0; m < 8; m++) {
    #pragma unroll
    for (int n = 0; n < 4; n++) {
      #pragma unroll
      for (int q = 0; q < 4; q++) {
        int row = orow0 + m * 16 + q;
        int col = ocol0 + n * 16;
        if (!GUARD_N || col < N) {
          float v = acc[m][n][q] + bias[col];
          if (OUT_MODE == 1) {
            ((u16*)Cout)[(size_t)row * ldc + col] = f2bf(v);
          } else if (OUT_MODE == 2) {               // wt bf16 [b][h][t][32]
            int bb = row >> 11, t = row & 2047;
            int hh = col / 31, kk = col - hh * 31;  // compile-time magic div
            ((u16*)Cout)[((size_t)((bb * NH + hh) * T_DIM + t)) * 32 + kk] = f2bf(v);
          } else {                                  // 3: conv layout bf16
            int bb = row >> 11, t = row & 2047;
            ((u16*)Cout)[(size_t)((bb << 4) + (col >> 6)) * SLICE + (size_t)t * 64 + (col & 63)] = f2bf(v);
          }
        }
      }
    }
  }
}

// ---------------------------------------------------------------- dynamic conv + fused softmax (TT=128, pair-share v2)
// R18-exact (best-measured: 88 us). Pair {pb, pb+1}, pb = half*64 + 2*tl:
// 64 shared b128 h-reads (vs 124), scalar stride-33 f32 w reads (conflict-free
// broadcasts). No res[] (separate ob buffer, immediate per-half stores);
// ob XOR-swizzled; global stores contiguous-4KB-per-instruction.
// R19 lesson: bf16 wl shrank LDS but occupancy didn't rise and the +124 cvt
// ops hit the 53%-busy VALU path -> regressed. f32 wl is the optimum.
__global__ __launch_bounds__(256) void dconv(const u16* __restrict__ h1,
                                             const u16* __restrict__ wt,
                                             const u16* __restrict__ zreg,
                                             u16* __restrict__ outc)
{
  constexpr int TT = 128, HALO = 30, SW = 33;
  int bid = blockIdx.x;
  int tt = bid & 15;            // T/128 = 16
  int b  = (bid >> 4) & 15;
  int h  = bid >> 8;            // 0..15
  int s  = b * 16 + h;
  int t0 = tt * TT;
  __shared__ u16 hl[(TT + HALO) * 64];   // 19.75 KB
  __shared__ float wl[TT * SW];          // 16.5 KB
  __shared__ u16 ob[TT * 64];            // 16 KB swizzled out-buffer
  int tid = threadIdx.x;

  const u16* slice = h1 + (size_t)s * SLICE;
  #pragma unroll
  for (int it = 0; it < 5; it++) {
    int c = it * 256 + tid;
    if (c < (TT + HALO) * 8) {
      int row = t0 - HALO + (c >> 3);
      const u16* src = slice + (size_t)row * 64 + (c & 7) * 8;
      if (row < 0) src = zreg + (c & 7) * 8;      // zeroed scratch
      GLDS(src, hl + c * 8);
    }
  }
  {
    const u16* wsrc = wt + ((size_t)s * T_DIM + t0) * 32;   // contiguous 8 KB bf16
    #pragma unroll
    for (int it = 0; it < 2; it++) {
      int j = (it * 256 + tid) * 8;
      us8 v = *(const us8*)(wsrc + j);
      int row = j >> 5, col = j & 31;
      #pragma unroll
      for (int e = 0; e < 8; e++) wl[row * SW + col + e] = bf2f(v[e]);
    }
  }
  __syncthreads();

  // fused softmax over the 128 staged rows (stride-33 rows -> conflict-free)
  if (tid < TT) {
    float* p = wl + tid * SW;
    float v[KSZ];
    float mx = -1e30f;
    #pragma unroll
    for (int k = 0; k < KSZ; k++) { v[k] = p[k]; mx = fmaxf(mx, v[k]); }
    float sum = 0.f;
    #pragma unroll
    for (int k = 0; k < KSZ; k++) { v[k] = __expf(v[k] - mx); sum += v[k]; }
    float inv = 1.0f / sum;
    #pragma unroll
    for (int k = 0; k < KSZ; k++) p[k] = v[k] * inv;
  }
  __syncthreads();

  const int rb = (tid & 7) * 8;      // channel sub-block
  const int tl = tid >> 3;           // 0..31

  #pragma unroll
  for (int half = 0; half < 2; half++) {
    const int pb = half * 64 + tl * 2;     // pair base row
    float acc0[8], acc1[8];
    #pragma unroll
    for (int e = 0; e < 8; e++) { acc0[e] = 0.f; acc1[e] = 0.f; }
    const float* w0 = wl + pb * SW;
    const float* w1 = w0 + SW;
    const u16* hb = hl + pb * 64 + rb;
    #pragma unroll
    for (int j = 0; j < 32; j++) {         // shared input rows pb..pb+31
      us8 hv = *(const us8*)(hb + j * 64);
      float hf[8];
      #pragma unroll
      for (int e = 0; e < 8; e++) hf[e] = bf2f(hv[e]);
      if (j <= 30) {
        float w = w0[j];
        #pragma unroll
        for (int e = 0; e < 8; e++) acc0[e] += w * hf[e];
      }
      if (j >= 1) {
        float w = w1[j - 1];
        #pragma unroll
        for (int e = 0; e < 8; e++) acc1[e] += w * hf[e];
      }
    }
    // store pair immediately into swizzled ob (no res[] -> low VGPR)
    us8 o0, o1;
    #pragma unroll
    for (int e = 0; e < 8; e++) { o0[e] = f2bf(acc0[e]); o1[e] = f2bf(acc1[e]); }
    *(us8*)(&ob[pb * 64 + (rb ^ ((pb & 7) << 3))]) = o0;
    *(us8*)(&ob[(pb + 1) * 64 + (rb ^ (((pb + 1) & 7) << 3))]) = o1;
  }
  __syncthreads();

  // contiguous global stores: byte offset = q*4096 + tid*16 (4 KB span/instr)
  #pragma unroll
  for (int q = 0; q < 4; q++) {
    const int tb = tl + q * 32;
    us8 o = *(const us8*)(&ob[tb * 64 + (rb ^ ((tb & 7) << 3))]);
    *(us8*)(outc + (size_t)s * SLICE + (size_t)(t0 + tb) * 64 + rb) = o;
  }
}

// ---------------------------------------------------------------- residual + LayerNorm (bf16 x + bf16 h)
__global__ __launch_bounds__(256) void ln_res(const u16* __restrict__ xb,
                                              const u16* __restrict__ hb,
                                              float* __restrict__ out,
                                              const float* __restrict__ gamma,
                                              const float* __restrict__ beta)
{
  int mp = blockIdx.x;                 // b*2048 + t
  int b = mp >> 11, t = mp & 2047;
  int xrow = t * 16 + b;
  const us4* xr = (const us4*)(xb + (size_t)mp * E_DIM);
  const us4* hr = (const us4*)(hb + (size_t)mp * E_DIM);
  fvec4* yr = (fvec4*)(out + (size_t)xrow * E_DIM);
  int tid = threadIdx.x;
  us4 hv = hr[tid];
  us4 xv = xr[tid];
  fvec4 s;
  #pragma unroll
  for (int e = 0; e < 4; e++) s[e] = bf2f(xv[e]) + bf2f(hv[e]);
  float sum = s[0] + s[1] + s[2] + s[3];
  float sq  = s[0]*s[0] + s[1]*s[1] + s[2]*s[2] + s[3]*s[3];
  #pragma unroll
  for (int off = 32; off >= 1; off >>= 1) {
    sum += __shfl_xor(sum, off, 64);
    sq  += __shfl_xor(sq, off, 64);
  }
  __shared__ float red[8];
  int lane = tid & 63, wid = tid >> 6;
  if (lane == 0) { red[wid] = sum; red[4 + wid] = sq; }
  __syncthreads();
  sum = red[0] + red[1] + red[2] + red[3];
  sq  = red[4] + red[5] + red[6] + red[7];
  float mean = sum * (1.0f / E_DIM);
  float var  = sq * (1.0f / E_DIM) - mean * mean;
  float rstd = rsqrtf(var + 1e-5f);
  fvec4 g = ((const fvec4*)gamma)[tid];
  fvec4 be = ((const fvec4*)beta)[tid];
  fvec4 o;
  #pragma unroll
  for (int e = 0; e < 4; e++) o[e] = (s[e] - mean) * rstd * g[e] + be[e];
  yr[tid] = o;
}

// ---------------------------------------------------------------- launcher
extern "C" void kernel_launch(void* const* d_in, const int* in_sizes, int n_in,
                              void* d_out, int out_size, void* d_ws, size_t ws_size,
                              hipStream_t stream)
{
  const float* x     = (const float*)d_in[0];
  const float* w1    = (const float*)d_in[1];
  const float* b1    = (const float*)d_in[2];
  const float* ww    = (const float*)d_in[3];
  const float* bw    = (const float*)d_in[4];
  const float* w2    = (const float*)d_in[5];
  const float* b2    = (const float*)d_in[6];
  const float* gamma = (const float*)d_in[7];
  const float* beta  = (const float*)d_in[8];
  float* out = (float*)d_out;

  char* ws = (char*)d_ws;
  u16*   xbt  = (u16*)(ws);                          // 64 MB  xb'[b][t][e] (kept for ln_res)
  u16*   h1p  = (u16*)(ws + ((size_t)64 << 20));     // 64 MB  h1'[s][t][64]; reused as h2'
  u16*   wt   = (u16*)(ws + ((size_t)128 << 20));    // 32 MB  wt[b][h][t][32] bf16 logits
  u16*   convp = (u16*)(ws + ((size_t)160 << 20));   // 64 MB  conv'
  u16*   w1b  = (u16*)(ws + ((size_t)224 << 20));    // 2 MB
  u16*   w2b  = (u16*)(ws + ((size_t)226 << 20));    // 2 MB
  u16*   wwb  = (u16*)(ws + ((size_t)228 << 20));    // ~1 MB
  u16*   zreg = (u16*)(ws + ((size_t)230 << 20));    // 4 KB zeroed
  u16*   h2p  = h1p;                                 // h1p dead after dconv

  prep<<<35313, 256, 0, stream>>>(x, w1, w2, ww, xbt, w1b, w2b, wwb, zreg);

  // h1' = x @ w1^T + b1   (conv-layout bf16); 256 M-tiles x 4 N-tiles
  gemm_tlp<3, 0, 0><<<1024, 256, 0, stream>>>(xbt, w1b, b1, h1p, CD, E_DIM, 0, 4);
  // wt[b][h][t][k] = h1' @ ww^T + bw   (bf16 logits, N=496 guarded); 256 x 2
  gemm_tlp<2, 1, 1><<<512, 256, 0, stream>>>(h1p, wwb, bw, wt, NH * KSZ, CD, 0, 2);
  dconv<<<4096, 256, 0, stream>>>(h1p, wt, zreg, convp);
  // h2' = conv' @ w2^T + b2   (bf16, rows m'); 256 x 4
  gemm_tlp<1, 0, 1><<<1024, 256, 0, stream>>>(convp, w2b, b2, h2p, E_DIM, CD, E_DIM, 4);
  ln_res<<<32768, 256, 0, stream>>>(xbt, h2p, out, gamma, beta);
}